// Round 8
// baseline (2594.422 us; speedup 1.0000x reference)
//
#include <hip/hip_runtime.h>
#include <math.h>

constexpr int DD    = 512;
constexpr int D2    = 1024;
constexpr int NTOK  = 256;
constexpr int NSYM  = 512;
constexpr int NCON  = 64;
constexpr int VOCAB = 256;
constexpr int BS_TOT = 16384;
constexpr int NDEPTH = 6;
constexpr int NLOOK  = 3;
constexpr int BLOCK = 512;
constexpr int SPLIT = 4;           // bitwise-matches round-4/6 partial sums
constexpr int KB    = D2 / SPLIT;  // 256
constexpr int LDT   = 68;
constexpr float EPSF = 1e-8f;
constexpr float SCALE = 0.044194173824159216f; // 512^-0.5

struct Params {
    const int* x;
    const float *mag, *phase, *Wr, *Wi, *qw, *qb, *kw, *kb, *vw, *vb, *dec_w, *dec_b, *sym, *con;
    float* out;
    float *bufA, *bufB, *Kmem, *Vmem, *rows, *CW, *qwT, *KVT, *symT, *decT, *conT;
    float *cellP, *QP, *symP, *kvP, *decP, *snorm, *conf, *symErr, *conErr;
    int* hist;
    unsigned* flags;   // 256 flags, 64B apart
    unsigned* go;
};

__device__ __forceinline__ void fma4(float4& a, const float4& w, float s) {
    a.x += w.x * s; a.y += w.y * s; a.z += w.z * s; a.w += w.w * s;
}

// Contention-free grid barrier: per-block arrival flags (separate cachelines),
// block 0 gathers in parallel, single 'go' epoch release.
__device__ __forceinline__ void gbar2(unsigned* flags, unsigned* go, unsigned ep,
                                      int bid, int gdim, int tid) {
    __syncthreads();
    if (tid == 0) {
        __threadfence();   // release: block's stores visible device-wide
        __hip_atomic_store(&flags[(size_t)bid * 16], ep,
                           __ATOMIC_RELEASE, __HIP_MEMORY_SCOPE_AGENT);
    }
    if (bid == 0) {
        for (int i = tid; i < gdim; i += BLOCK)
            while (__hip_atomic_load(&flags[(size_t)i * 16],
                                     __ATOMIC_ACQUIRE, __HIP_MEMORY_SCOPE_AGENT) < ep)
                __builtin_amdgcn_s_sleep(2);
        __syncthreads();
        if (tid == 0)
            __hip_atomic_store(go, ep, __ATOMIC_RELEASE, __HIP_MEMORY_SCOPE_AGENT);
    }
    if (tid == 0) {
        while (__hip_atomic_load(go, __ATOMIC_ACQUIRE, __HIP_MEMORY_SCOPE_AGENT) < ep)
            __builtin_amdgcn_s_sleep(2);
        __threadfence();   // acquire: see other blocks' stores
    }
    __syncthreads();
}

__device__ __forceinline__ float cepi1(float lr, float li, bool hi) {
    float m = sqrtf(lr * lr + li * li + EPSF);
    float inv = 1.0f / (1.0f + m);
    return hi ? tanhf(li * inv) : tanhf(lr * inv);
}

// Tiled GEMM: P[s][t][j] = sum_{k in slice s} X[t][k]*WT[k][j].
// FROMP: X := cellP partials; stage values recomputed via cellepi (bitwise identical).
template<bool FROMP>
__device__ void gemm_tiles(const float* __restrict__ WT, const float* __restrict__ X,
                           float* __restrict__ Pout, int N, int njt,
                           int bid, int gdim, int tid, float* sX, float* sW) {
    int total = njt * 4 * SPLIT;
    int jq = tid & 15;
    int tq = tid >> 4;
    for (int tile = bid; tile < total; tile += gdim) {
        int jt = tile % njt;
        int r  = tile / njt;
        int tt = r & 3;
        int s  = r >> 2;
        int j0 = jt * 64, t0 = tt * 64, k0 = s * KB;
        float4 a0 = {0,0,0,0}, a1 = {0,0,0,0};
        for (int kc = 0; kc < KB / 32; ++kc) {
            int kbase = k0 + kc * 32;
            __syncthreads();
            {
                int t = tid >> 3, kq = tid & 7;
                float4 v;
                if (!FROMP) {
                    v = *(const float4*)&X[(size_t)(t0 + t) * D2 + kbase + kq * 4];
                } else {
                    int kb4 = kbase + kq * 4;
                    bool hi = kb4 >= DD;
                    int lo = hi ? kb4 - DD : kb4;
                    float4 lr = {0,0,0,0}, li = {0,0,0,0};
#pragma unroll
                    for (int ss = 0; ss < SPLIT; ++ss) {
                        const float* bp = X + ((size_t)ss * NTOK + (t0 + t)) * D2;
                        float4 a = *(const float4*)&bp[lo];
                        float4 b = *(const float4*)&bp[lo + DD];
                        lr.x += a.x; lr.y += a.y; lr.z += a.z; lr.w += a.w;
                        li.x += b.x; li.y += b.y; li.z += b.z; li.w += b.w;
                    }
                    v.x = cepi1(lr.x, li.x, hi);
                    v.y = cepi1(lr.y, li.y, hi);
                    v.z = cepi1(lr.z, li.z, hi);
                    v.w = cepi1(lr.w, li.w, hi);
                }
                sX[(kq * 4 + 0) * LDT + t] = v.x;
                sX[(kq * 4 + 1) * LDT + t] = v.y;
                sX[(kq * 4 + 2) * LDT + t] = v.z;
                sX[(kq * 4 + 3) * LDT + t] = v.w;
                int kw_ = tid >> 4, j4 = tid & 15;
                *(float4*)&sW[kw_ * LDT + j4 * 4] =
                    *(const float4*)&WT[(size_t)(kbase + kw_) * N + j0 + j4 * 4];
            }
            __syncthreads();
#pragma unroll 8
            for (int k = 0; k < 32; ++k) {
                float x0 = sX[k * LDT + tq * 2];
                float x1 = sX[k * LDT + tq * 2 + 1];
                float4 wb = *(const float4*)&sW[k * LDT + jq * 4];
                fma4(a0, wb, x0);
                fma4(a1, wb, x1);
            }
        }
        size_t base = ((size_t)s * NTOK + (t0 + tq * 2)) * N + j0 + jq * 4;
        *(float4*)&Pout[base]     = a0;
        *(float4*)&Pout[base + N] = a1;
    }
}

__device__ void transpose_tiles(const float* __restrict__ in, float* __restrict__ outp,
                                int R, int C, int ldo, int bid, int gdim, int tid, float* sm) {
    int tcx = C >> 5, total = tcx * (R >> 5);
    float (*t)[33] = (float(*)[33])sm;
    int xx = tid & 31, yy = tid >> 5;   // yy 0..15
    for (int tile = bid; tile < total; tile += gdim) {
        int c0 = (tile % tcx) * 32, r0 = (tile / tcx) * 32;
        __syncthreads();
#pragma unroll
        for (int i = 0; i < 32; i += 16)
            t[yy + i][xx] = in[(size_t)(r0 + yy + i) * C + c0 + xx];
        __syncthreads();
#pragma unroll
        for (int i = 0; i < 32; i += 16)
            outp[(size_t)(c0 + yy + i) * ldo + r0 + xx] = t[xx][yy + i];
    }
}

__device__ void buildcw(const float* __restrict__ Wr, const float* __restrict__ Wi,
                        float* __restrict__ CW, int bid, int gdim, int tid, float* sm) {
    float (*tr)[33] = (float(*)[33])sm;
    float (*ti)[33] = (float(*)[33])(sm + 1056);
    int xx = tid & 31, yy = tid >> 5;
    for (int tile = bid; tile < 256; tile += gdim) {
        int j0 = (tile & 15) * 32, k0 = (tile >> 4) * 32;
        __syncthreads();
#pragma unroll
        for (int i = 0; i < 32; i += 16) {
            tr[yy + i][xx] = Wr[(size_t)(j0 + yy + i) * DD + k0 + xx];
            ti[yy + i][xx] = Wi[(size_t)(j0 + yy + i) * DD + k0 + xx];
        }
        __syncthreads();
#pragma unroll
        for (int i = 0; i < 32; i += 16) {
            float vr = tr[xx][yy + i], vi = ti[xx][yy + i];
            int k = k0 + yy + i, j = j0 + xx;
            CW[(size_t)k * D2 + j]             = vr;
            CW[(size_t)k * D2 + DD + j]        = vi;
            CW[(size_t)(DD + k) * D2 + j]      = -vi;
            CW[(size_t)(DD + k) * D2 + DD + j] = vr;
        }
    }
}

__device__ void cellepi_stage(const float* __restrict__ P, float* __restrict__ z,
                              int bid, int gdim, int tid) {
    for (int t = bid; t < NTOK; t += gdim) {
        int j = tid;
        float lr = 0.f, li = 0.f;
#pragma unroll
        for (int s = 0; s < SPLIT; ++s) {
            lr += P[((size_t)s * NTOK + t) * D2 + j];
            li += P[((size_t)s * NTOK + t) * D2 + DD + j];
        }
        float m = sqrtf(lr * lr + li * li + EPSF);
        float inv = 1.0f / (1.0f + m);
        z[(size_t)t * D2 + j]      = tanhf(lr * inv);
        z[(size_t)t * D2 + DD + j] = tanhf(li * inv);
    }
}

__device__ void kvcomb_stage(const Params& p, int slot, int bid, int gdim, int tid) {
    for (int w2 = bid; w2 < NTOK * 3; w2 += gdim) {
        int t = w2 / 3;
        int e = (w2 % 3) * 512 + tid;
        float v = 0.f;
#pragma unroll
        for (int s = 0; s < SPLIT; ++s)
            v += p.kvP[((size_t)s * NTOK + t) * 1536 + e];
        if (e < DD) p.Kmem[((size_t)slot * NTOK + t) * DD + e] = v + p.kb[e];
        else        p.Vmem[((size_t)slot * NTOK + t) * D2 + (e - DD)] = v + p.vb[e - DD];
    }
}

__device__ void attend_stage(const Params& p, float* __restrict__ z, int M,
                             int bid, int gdim, int tid, float* sm) {
    float* red  = sm;
    float* s_sc = sm + 512;
    for (int v = bid; v < NTOK; v += gdim) {
        float q0 = 0.f, q1 = 0.f;
        if (tid < 256) {
#pragma unroll
            for (int s = 0; s < SPLIT; ++s) {
                q0 += p.QP[((size_t)s * NTOK + v) * DD + tid];
                q1 += p.QP[((size_t)s * NTOK + v) * DD + 256 + tid];
            }
            q0 += p.qb[tid];
            q1 += p.qb[256 + tid];
        }
        for (int m = 0; m < M; ++m) {
            const float* K = p.Kmem + (size_t)m * NTOK * DD + (size_t)v * DD;
            __syncthreads();
            if (tid < 256) red[tid] = q0 * K[tid] + q1 * K[256 + tid];
            __syncthreads();
            for (int off = 128; off > 0; off >>= 1) {
                if (tid < off) red[tid] += red[tid + off];
                __syncthreads();
            }
            if (tid == 0) s_sc[m] = red[0] * SCALE * p.conf[v];
            __syncthreads();
        }
        if (tid == 0) {
            float mx = s_sc[0];
            for (int m = 1; m < M; ++m) mx = fmaxf(mx, s_sc[m]);
            float w[8], sum = 0.f;
            for (int m = 0; m < M; ++m) { w[m] = expf(s_sc[m] - mx); sum += w[m]; }
            for (int m = 0; m < M; ++m) s_sc[m] = w[m] / sum;
        }
        __syncthreads();
#pragma unroll
        for (int r = 0; r < 2; ++r) {
            int e = r * 512 + tid;
            float ctx = 0.f;
            for (int m = 0; m < M; ++m)
                ctx += s_sc[m] * p.Vmem[(size_t)m * NTOK * D2 + (size_t)v * D2 + e];
            z[(size_t)v * D2 + e] += 0.1f * ctx;
        }
        __syncthreads();
    }
}

__device__ void finish_stage(const Params& p, float* __restrict__ z,
                             int bid, int gdim, int tid, float* sm) {
    float* s_z   = sm;                     // 1024
    float* s_red = sm + 1024;              // 512
    int*   s_idx = (int*)(sm + 1536);      // 512
    float* s_pd  = sm + 2048;              // 256
    float* s_pc  = sm + 2304;              // 256
    float* s_res = sm + 2560;              // 4
    int*   s_si  = (int*)(sm + 2564);

    for (int t0 = bid; t0 < NTOK; t0 += gdim) {
        __syncthreads();
        if (tid < 256) ((float4*)s_z)[tid] = ((const float4*)(z + (size_t)t0 * D2))[tid];
        __syncthreads();

        // ||z||^2
        {
            float a = s_z[tid], b = s_z[512 + tid];
            s_red[tid] = a * a + b * b;
            __syncthreads();
            for (int off = 256; off > 0; off >>= 1) {
                if (tid < off) s_red[tid] += s_red[tid + off];
                __syncthreads();
            }
            if (tid == 0) s_res[0] = s_red[0];
            __syncthreads();
        }

        // sym distance + argmin (first-min tie-break)
        {
            float dot = 0.f;
#pragma unroll
            for (int s = 0; s < SPLIT; ++s)
                dot += p.symP[((size_t)s * NTOK + t0) * NSYM + tid];
            float d = (s_res[0] + p.snorm[tid]) - 2.f * dot;
            s_red[tid] = d; s_idx[tid] = tid;
            __syncthreads();
            for (int off = 256; off > 0; off >>= 1) {
                if (tid < off) {
                    float o = s_red[tid + off]; int oi = s_idx[tid + off];
                    if (o < s_red[tid] || (o == s_red[tid] && oi < s_idx[tid])) {
                        s_red[tid] = o; s_idx[tid] = oi;
                    }
                }
                __syncthreads();
            }
            if (tid == 0) { s_res[1] = s_red[0]; s_si[0] = s_idx[0]; }
            __syncthreads();
        }

        // conf, straight-through update, symErr
        {
            int si = s_si[0];
            if (tid == 0) p.conf[t0] = 1.0f / (1.0f + s_res[1]);
            const float* crow = p.sym + (size_t)si * D2;
            float errp = 0.f;
#pragma unroll
            for (int r = 0; r < 2; ++r) {
                int e = r * 512 + tid;
                float zf = s_z[e];
                float diff = crow[e] - zf;
                errp += diff * diff;
                float zn = zf + diff;      // zs = z + (c - z)
                s_z[e] = zn;
                z[(size_t)t0 * D2 + e] = zn;
            }
            s_red[tid] = errp;
            __syncthreads();
            for (int off = 256; off > 0; off >>= 1) {
                if (tid < off) s_red[tid] += s_red[tid + off];
                __syncthreads();
            }
            if (tid == 0) p.symErr[t0] += s_red[0];
            __syncthreads();
        }

        // ||zs||^2
        {
            float a = s_z[tid], b = s_z[512 + tid];
            s_red[tid] = a * a + b * b;
            __syncthreads();
            for (int off = 256; off > 0; off >>= 1) {
                if (tid < off) s_red[tid] += s_red[tid + off];
                __syncthreads();
            }
            if (tid == 0) s_res[2] = s_red[0];
            __syncthreads();
        }

        // con quantize
        if (tid < 256) {
            int c = tid & 63, sl = tid >> 6;
            float pd = 0.f, pc = 0.f;
            int k0 = sl * 256;
#pragma unroll 4
            for (int k = k0; k < k0 + 256; ++k) {
                float w = p.conT[(size_t)k * NCON + c];
                pd += w * s_z[k];
                pc += w * w;
            }
            s_pd[tid] = pd; s_pc[tid] = pc;
        }
        __syncthreads();
        if (tid < 64) {
            float dot = ((s_pd[tid] + s_pd[64 + tid]) + s_pd[128 + tid]) + s_pd[192 + tid];
            float cn2 = ((s_pc[tid] + s_pc[64 + tid]) + s_pc[128 + tid]) + s_pc[192 + tid];
            s_red[tid] = (s_res[2] + cn2) - 2.f * dot;
            s_idx[tid] = tid;
        }
        __syncthreads();
        for (int off = 32; off > 0; off >>= 1) {
            if (tid < off) {
                float o = s_red[tid + off]; int oi = s_idx[tid + off];
                if (o < s_red[tid] || (o == s_red[tid] && oi < s_idx[tid])) {
                    s_red[tid] = o; s_idx[tid] = oi;
                }
            }
            __syncthreads();
        }
        int ci0 = s_idx[0];
        __syncthreads();

        // conErr
        {
            const float* crow = p.con + (size_t)ci0 * D2;
            float pp = 0.f;
#pragma unroll
            for (int r = 0; r < 2; ++r) {
                int e = r * 512 + tid;
                float diff = crow[e] - s_z[e];
                pp += diff * diff;
            }
            s_red[tid] = pp;
            __syncthreads();
            for (int off = 256; off > 0; off >>= 1) {
                if (tid < off) s_red[tid] += s_red[tid + off];
                __syncthreads();
            }
            if (tid == 0) p.conErr[t0] += s_red[0];
            __syncthreads();
        }
    }
}

__global__ __launch_bounds__(BLOCK, 1) void mega_kernel(Params p) {
    __shared__ __align__(16) float sm[4352];    // 17408 B
    int bid = blockIdx.x, tid = threadIdx.x;
    const int gdim = gridDim.x;
    unsigned ep = 0;
    float* sX = sm;
    float* sW = sm + 2176;

    // ---------- setup ----------
    if (bid == gdim - 1 && tid < 256) { p.symErr[tid] = 0.f; p.conErr[tid] = 0.f; p.hist[tid] = 0; }
    for (int v = bid; v < NTOK; v += gdim) {
        float r = p.mag[(size_t)v * DD + tid], t = p.phase[(size_t)v * DD + tid];
        p.bufA[(size_t)v * D2 + tid]      = r * cosf(t);
        p.bufA[(size_t)v * D2 + DD + tid] = r * sinf(t);
    }
    for (int c = bid; c < NSYM; c += gdim) {
        __syncthreads();
        if (tid < 256) {
            float4 v = ((const float4*)(p.sym + (size_t)c * D2))[tid];
            sm[tid] = v.x*v.x + v.y*v.y + v.z*v.z + v.w*v.w;
        }
        __syncthreads();
        for (int off = 128; off > 0; off >>= 1) {
            if (tid < off) sm[tid] += sm[tid + off];
            __syncthreads();
        }
        if (tid == 0) p.snorm[c] = sm[0];
    }
    transpose_tiles(p.qw,    p.qwT,      DD,    D2, DD,    bid, gdim, tid, sm);
    transpose_tiles(p.kw,    p.KVT,      DD,    D2, 1536,  bid, gdim, tid, sm);
    transpose_tiles(p.vw,    p.KVT + DD, D2,    D2, 1536,  bid, gdim, tid, sm);
    transpose_tiles(p.sym,   p.symT,     NSYM,  D2, NSYM,  bid, gdim, tid, sm);
    transpose_tiles(p.dec_w, p.decT,     VOCAB, D2, VOCAB, bid, gdim, tid, sm);
    transpose_tiles(p.con,   p.conT,     NCON,  D2, NCON,  bid, gdim, tid, sm);
    buildcw(p.Wr, p.Wi, p.CW, bid, gdim, tid, sm);
    ep++; gbar2(p.flags, p.go, ep, bid, gdim, tid);

    float* cur = p.bufA;
    float* oth = p.bufB;
    for (int d = 0; d < NDEPTH; ++d) {
        // S1: cellgemm (+ hist at d0, + kvgemm slot d-1 at d>0) — all read `cur`
        if (d == 0) {
            for (int i = bid * BLOCK + tid; i < BS_TOT; i += gdim * BLOCK)
                atomicAdd(&p.hist[p.x[i]], 1);
        } else {
            gemm_tiles<false>(p.KVT, cur, p.kvP, 1536, 24, bid, gdim, tid, sX, sW);
        }
        gemm_tiles<false>(p.CW, cur, p.cellP, D2, 16, bid, gdim, tid, sX, sW);
        ep++; gbar2(p.flags, p.go, ep, bid, gdim, tid);

        // S2: cellepi + kvcomb + qgemm (X recomputed from cellP partials)
        cellepi_stage(p.cellP, oth, bid, gdim, tid);
        if (d > 0) {
            kvcomb_stage(p, d - 1, bid, gdim, tid);
            gemm_tiles<true>(p.qwT, p.cellP, p.QP, DD, 8, bid, gdim, tid, sX, sW);
        }
        { float* t_ = cur; cur = oth; oth = t_; }
        ep++; gbar2(p.flags, p.go, ep, bid, gdim, tid);

        // S3: attend (d>0)
        if (d > 0) {
            attend_stage(p, cur, d, bid, gdim, tid, sm);
            ep++; gbar2(p.flags, p.go, ep, bid, gdim, tid);
        }

        // S4: symgemm
        gemm_tiles<false>(p.symT, cur, p.symP, NSYM, 8, bid, gdim, tid, sX, sW);
        ep++; gbar2(p.flags, p.go, ep, bid, gdim, tid);

        // S5: finish
        finish_stage(p, cur, bid, gdim, tid, sm);
        ep++; gbar2(p.flags, p.go, ep, bid, gdim, tid);
    }

    for (int l = 0; l < NLOOK; ++l) {
        gemm_tiles<false>(p.CW, cur, p.cellP, D2, 16, bid, gdim, tid, sX, sW);
        ep++; gbar2(p.flags, p.go, ep, bid, gdim, tid);
        cellepi_stage(p.cellP, oth, bid, gdim, tid);
        { float* t_ = cur; cur = oth; oth = t_; }
        ep++; gbar2(p.flags, p.go, ep, bid, gdim, tid);
    }

    gemm_tiles<false>(p.decT, cur, p.decP, VOCAB, 4, bid, gdim, tid, sX, sW);
    ep++; gbar2(p.flags, p.go, ep, bid, gdim, tid);

    for (int t = bid; t < NTOK; t += gdim) {
        if (tid < 256) {
            float v = 0.f;
#pragma unroll
            for (int s = 0; s < SPLIT; ++s)
                v += p.decP[((size_t)s * NTOK + t) * VOCAB + tid];
            p.rows[(size_t)t * VOCAB + tid] = v + p.dec_b[tid];
        }
    }
    ep++; gbar2(p.flags, p.go, ep, bid, gdim, tid);

    // scatter
    for (size_t i = (size_t)bid * BLOCK + tid; i < (size_t)BS_TOT * 64; i += (size_t)gdim * BLOCK) {
        int pos = (int)(i >> 6), lane = (int)(i & 63);
        int v = p.x[pos];
        ((float4*)(p.out + (size_t)pos * VOCAB))[lane] =
            ((const float4*)(p.rows + (size_t)v * VOCAB))[lane];
    }

    // losses
    if (bid == 0) {
        double* rs = (double*)sm;
        double* rc = rs + 256;
        __syncthreads();
        if (tid < 256) {
            rs[tid] = (double)p.hist[tid] * (double)p.symErr[tid];
            rc[tid] = (double)p.hist[tid] * (double)p.conErr[tid];
        }
        __syncthreads();
        for (int off = 128; off > 0; off >>= 1) {
            if (tid < off) { rs[tid] += rs[tid + off]; rc[tid] += rc[tid + off]; }
            __syncthreads();
        }
        if (tid == 0) {
            const double denom = (double)BS_TOT * (double)D2;
            p.out[(size_t)BS_TOT * VOCAB]     = (float)(1.25 * rs[0] / denom);
            p.out[(size_t)BS_TOT * VOCAB + 1] = (float)(1.25 * rc[0] / denom);
        }
    }
}

extern "C" void kernel_launch(void* const* d_in, const int* in_sizes, int n_in,
                              void* d_out, int out_size, void* d_ws, size_t ws_size,
                              hipStream_t stream) {
    Params p;
    p.x     = (const int*)  d_in[0];
    p.mag   = (const float*)d_in[1];
    p.phase = (const float*)d_in[2];
    p.Wr    = (const float*)d_in[3];
    p.Wi    = (const float*)d_in[4];
    p.qw    = (const float*)d_in[5];
    p.qb    = (const float*)d_in[6];
    p.kw    = (const float*)d_in[7];
    p.kb    = (const float*)d_in[8];
    p.vw    = (const float*)d_in[9];
    p.vb    = (const float*)d_in[10];
    p.dec_w = (const float*)d_in[11];
    p.dec_b = (const float*)d_in[12];
    p.sym   = (const float*)d_in[13];
    p.con   = (const float*)d_in[14];
    p.out   = (float*)d_out;

    p.flags = (unsigned*)d_ws;               // 256 * 16 u32 = 16 KB
    p.go    = p.flags + 256 * 16;            // own cacheline
    float* w = (float*)d_ws + 256 * 16 + 16;
    auto take = [&](size_t n) { float* r = w; w += n; return r; };
    p.bufA   = take((size_t)NTOK * D2);
    p.bufB   = take((size_t)NTOK * D2);
    p.Kmem   = take((size_t)NDEPTH * NTOK * DD);
    p.Vmem   = take((size_t)NDEPTH * NTOK * D2);
    p.rows   = take((size_t)NTOK * VOCAB);
    p.CW     = take((size_t)D2 * D2);
    p.qwT    = take((size_t)D2 * DD);
    p.KVT    = take((size_t)D2 * 1536);
    p.symT   = take((size_t)D2 * NSYM);
    p.decT   = take((size_t)D2 * VOCAB);
    p.conT   = take((size_t)D2 * NCON);
    p.cellP  = take((size_t)SPLIT * NTOK * D2);
    p.QP     = take((size_t)SPLIT * NTOK * DD);
    p.symP   = take((size_t)SPLIT * NTOK * NSYM);
    p.kvP    = take((size_t)SPLIT * NTOK * 1536);
    p.decP   = take((size_t)SPLIT * NTOK * VOCAB);
    p.snorm  = take(NSYM);
    p.conf   = take(NTOK);
    p.symErr = take(NTOK);
    p.conErr = take(NTOK);
    p.hist   = (int*)take(NTOK);

    // Grid must be fully co-resident: 512-thread blocks, 1/CU minimum.
    int maxb = 0;
    hipError_t oe = hipOccupancyMaxActiveBlocksPerMultiprocessor(
        &maxb, (const void*)mega_kernel, BLOCK, 0);
    int grid = 256;
    if (oe == hipSuccess && maxb >= 1) {
        long cap = (long)maxb * 256;
        if (cap < grid) grid = (int)cap;
    }

    hipMemsetAsync((void*)p.flags, 0, (256 * 16 + 16) * sizeof(unsigned), stream);
    mega_kernel<<<grid, BLOCK, 0, stream>>>(p);
}

// Round 9
// 892.435 us; speedup vs baseline: 2.9071x; 2.9071x over previous
//
#include <hip/hip_runtime.h>
#include <math.h>

constexpr int DD    = 512;
constexpr int D2    = 1024;
constexpr int NTOK  = 256;
constexpr int NSYM  = 512;
constexpr int NCON  = 64;
constexpr int VOCAB = 256;
constexpr int BS_TOT = 16384;
constexpr int NDEPTH = 6;
constexpr int NLOOK  = 3;
constexpr int SPLIT = 4;           // bitwise-matches round-4 partial sums
constexpr int KB    = D2 / SPLIT;  // 256
constexpr int LDT   = 68;
constexpr int LDKV  = 2560;        // CKV / P2 row stride: [cell 1024 | K 512 | V 1024]
constexpr float EPSF = 1e-8f;
constexpr float SCALE = 0.044194173824159216f; // 512^-0.5

__device__ __forceinline__ void fma4(float4& a, const float4& w, float s) {
    a.x += w.x * s; a.y += w.y * s; a.z += w.z * s; a.w += w.w * s;
}

__device__ __forceinline__ float cepi1(float lr, float li, bool hi) {
    float m = sqrtf(lr * lr + li * li + EPSF);
    float inv = 1.0f / (1.0f + m);
    return hi ? tanhf(li * inv) : tanhf(lr * inv);
}

// ---------------- fused setup: embed, transposes, CKV build, symnorm, zero ----------------
__device__ void tposeB(const float* __restrict__ in, float* __restrict__ outp,
                       int R, int C, int ldo, int bid, int gdim, int tid, float* sm) {
    float (*t)[33] = (float(*)[33])sm;
    int xx = tid & 31, yy = tid >> 5;       // block 256: yy 0..7
    int tcx = C >> 5, total = tcx * (R >> 5);
    for (int tile = bid; tile < total; tile += gdim) {
        int c0 = (tile % tcx) * 32, r0 = (tile / tcx) * 32;
        __syncthreads();
#pragma unroll
        for (int i = 0; i < 32; i += 8)
            t[yy + i][xx] = in[(size_t)(r0 + yy + i) * C + c0 + xx];
        __syncthreads();
#pragma unroll
        for (int i = 0; i < 32; i += 8)
            outp[(size_t)(c0 + yy + i) * ldo + r0 + xx] = t[xx][yy + i];
    }
}

__global__ __launch_bounds__(256) void setup_kernel(const float* __restrict__ mag,
                                                    const float* __restrict__ phase,
                                                    const float* __restrict__ Wr,
                                                    const float* __restrict__ Wi,
                                                    const float* __restrict__ qw,
                                                    const float* __restrict__ kw,
                                                    const float* __restrict__ vw,
                                                    const float* __restrict__ dec_w,
                                                    const float* __restrict__ sym,
                                                    const float* __restrict__ con,
                                                    float* __restrict__ z,
                                                    float* __restrict__ CKV,
                                                    float* __restrict__ qwT,
                                                    float* __restrict__ symT,
                                                    float* __restrict__ decT,
                                                    float* __restrict__ conT,
                                                    float* __restrict__ snorm,
                                                    float* __restrict__ symErr,
                                                    float* __restrict__ conErr) {
    __shared__ __align__(16) float sm[2112];
    int bid = blockIdx.x, tid = threadIdx.x, g = gridDim.x;
    if (bid == 0) { symErr[tid] = 0.f; conErr[tid] = 0.f; }
    // embed (v = bid; round-4 bitwise per element)
    {
        int v = bid;
#pragma unroll
        for (int h = 0; h < 2; ++h) {
            int j = tid + h * 256;
            float r = mag[(size_t)v * DD + j], t = phase[(size_t)v * DD + j];
            z[(size_t)v * D2 + j]      = r * cosf(t);
            z[(size_t)v * D2 + DD + j] = r * sinf(t);
        }
    }
    // sym code norms (round-4 bitwise reduction)
    for (int c = bid; c < NSYM; c += g) {
        __syncthreads();
        float4 v = ((const float4*)(sym + (size_t)c * D2))[tid];
        sm[tid] = v.x*v.x + v.y*v.y + v.z*v.z + v.w*v.w;
        __syncthreads();
        for (int off = 128; off; off >>= 1) { if (tid < off) sm[tid] += sm[tid + off]; __syncthreads(); }
        if (tid == 0) snorm[c] = sm[0];
    }
    // transposes
    tposeB(qw,    qwT,        DD,    D2, DD,    bid, g, tid, sm);
    tposeB(kw,    CKV + 1024, DD,    D2, LDKV,  bid, g, tid, sm);
    tposeB(vw,    CKV + 1536, D2,    D2, LDKV,  bid, g, tid, sm);
    tposeB(sym,   symT,       NSYM,  D2, NSYM,  bid, g, tid, sm);
    tposeB(dec_w, decT,       VOCAB, D2, VOCAB, bid, g, tid, sm);
    tposeB(con,   conT,       NCON,  D2, NCON,  bid, g, tid, sm);
    // build combined cell weight into CKV cols 0..1024
    {
        float (*tr)[33] = (float(*)[33])sm;
        float (*ti)[33] = (float(*)[33])(sm + 1056);
        int xx = tid & 31, yy = tid >> 5;
        for (int tile = bid; tile < 256; tile += g) {
            int j0 = (tile & 15) * 32, k0 = (tile >> 4) * 32;
            __syncthreads();
#pragma unroll
            for (int i = 0; i < 32; i += 8) {
                tr[yy + i][xx] = Wr[(size_t)(j0 + yy + i) * DD + k0 + xx];
                ti[yy + i][xx] = Wi[(size_t)(j0 + yy + i) * DD + k0 + xx];
            }
            __syncthreads();
#pragma unroll
            for (int i = 0; i < 32; i += 8) {
                float vr = tr[xx][yy + i], vi = ti[xx][yy + i];
                int k = k0 + yy + i, j = j0 + xx;
                CKV[(size_t)k * LDKV + j]             = vr;
                CKV[(size_t)k * LDKV + DD + j]        = vi;
                CKV[(size_t)(DD + k) * LDKV + j]      = -vi;
                CKV[(size_t)(DD + k) * LDKV + DD + j] = vr;
            }
        }
    }
}

// ---------------- tiled GEMM (round-4 gemm64, bitwise), optional FROMX epi staging ----------
// P[s][t][j0..] = sum_{k in slice s} X[t][k]*WT[k][j]. grid (njt, 4, SPLIT), block 256.
// FROMX: X = split-K partials (ld ldx); staged values are the recomputed cell epilogue.
template<bool FROMX>
__global__ __launch_bounds__(256) void gemm_kernel(const float* __restrict__ WT, int ldw,
                                                   const float* __restrict__ X, int ldx,
                                                   float* __restrict__ Pout, int ldp) {
    __shared__ __align__(16) float sX[32 * LDT];
    __shared__ __align__(16) float sW[32 * LDT];
    int tid = threadIdx.x;
    int j0 = blockIdx.x * 64;
    int t0 = blockIdx.y * 64;
    int s  = blockIdx.z;
    int k0 = s * KB;
    int jq = tid & 15;
    int tq = tid >> 4;
    float4 a0 = {0,0,0,0}, a1 = {0,0,0,0}, a2 = {0,0,0,0}, a3 = {0,0,0,0};
    for (int kc = 0; kc < KB / 32; ++kc) {
        int kbase = k0 + kc * 32;
        __syncthreads();
#pragma unroll
        for (int b = 0; b < 2; ++b) {
            int f = tid * 2 + b;
            int t = f >> 3, kq = f & 7;
            float4 v;
            if (!FROMX) {
                v = *(const float4*)&X[(size_t)(t0 + t) * ldx + kbase + kq * 4];
            } else {
                int kb4 = kbase + kq * 4;
                bool hi = kb4 >= DD;
                int lo = hi ? kb4 - DD : kb4;
                float4 lr = {0,0,0,0}, li = {0,0,0,0};
#pragma unroll
                for (int ss = 0; ss < SPLIT; ++ss) {
                    const float* bp = X + ((size_t)ss * NTOK + (t0 + t)) * ldx;
                    float4 a = *(const float4*)&bp[lo];
                    float4 c = *(const float4*)&bp[lo + DD];
                    lr.x += a.x; lr.y += a.y; lr.z += a.z; lr.w += a.w;
                    li.x += c.x; li.y += c.y; li.z += c.z; li.w += c.w;
                }
                v.x = cepi1(lr.x, li.x, hi);
                v.y = cepi1(lr.y, li.y, hi);
                v.z = cepi1(lr.z, li.z, hi);
                v.w = cepi1(lr.w, li.w, hi);
            }
            sX[(kq * 4 + 0) * LDT + t] = v.x;
            sX[(kq * 4 + 1) * LDT + t] = v.y;
            sX[(kq * 4 + 2) * LDT + t] = v.z;
            sX[(kq * 4 + 3) * LDT + t] = v.w;
            int kw_ = f >> 4, j4 = f & 15;
            *(float4*)&sW[kw_ * LDT + j4 * 4] =
                *(const float4*)&WT[(size_t)(kbase + kw_) * ldw + j0 + j4 * 4];
        }
        __syncthreads();
#pragma unroll 8
        for (int k = 0; k < 32; ++k) {
            float4 xa = *(const float4*)&sX[k * LDT + tq * 4];
            float4 wb = *(const float4*)&sW[k * LDT + jq * 4];
            fma4(a0, wb, xa.x);
            fma4(a1, wb, xa.y);
            fma4(a2, wb, xa.z);
            fma4(a3, wb, xa.w);
        }
    }
    size_t base = ((size_t)s * NTOK + (t0 + tq * 4)) * ldp + j0 + jq * 4;
    *(float4*)&Pout[base]           = a0;
    *(float4*)&Pout[base + ldp]     = a1;
    *(float4*)&Pout[base + 2 * (size_t)ldp] = a2;
    *(float4*)&Pout[base + 3 * (size_t)ldp] = a3;
}

// ---------------- attend: kvcomb(slot M-1) + scores + softmax + z from epi + ctx ----------
// grid 256 (token), block 256. M = memory entries (slot M-1 combined here from P2).
__global__ __launch_bounds__(256) void attend_kernel(float* __restrict__ z,
                                                     const float* __restrict__ P2,
                                                     const float* __restrict__ QP,
                                                     const float* __restrict__ qb,
                                                     const float* __restrict__ kb,
                                                     const float* __restrict__ vb,
                                                     float* __restrict__ Kmem,
                                                     float* __restrict__ Vmem,
                                                     const float* __restrict__ conf,
                                                     int M) {
    int v = blockIdx.x, tid = threadIdx.x;
    __shared__ float red[256];
    __shared__ float s_sc[8];
    // kv combine for slot M-1 (each thread later reads exactly the elements it writes)
#pragma unroll
    for (int it = 0; it < 6; ++it) {
        int e = it * 256 + tid;
        float val = 0.f;
#pragma unroll
        for (int ss = 0; ss < SPLIT; ++ss)
            val += P2[((size_t)ss * NTOK + v) * LDKV + 1024 + e];
        if (e < DD) Kmem[((size_t)(M - 1) * NTOK + v) * DD + e] = val + kb[e];
        else        Vmem[((size_t)(M - 1) * NTOK + v) * D2 + (e - DD)] = val + vb[e - DD];
    }
    float q0 = 0.f, q1 = 0.f;
#pragma unroll
    for (int s = 0; s < SPLIT; ++s) {
        q0 += QP[((size_t)s * NTOK + v) * DD + tid];
        q1 += QP[((size_t)s * NTOK + v) * DD + 256 + tid];
    }
    q0 += qb[tid];
    q1 += qb[256 + tid];
    __syncthreads();
    for (int m = 0; m < M; ++m) {
        const float* K = Kmem + (size_t)m * NTOK * DD + (size_t)v * DD;
        red[tid] = q0 * K[tid] + q1 * K[256 + tid];
        __syncthreads();
        for (int off = 128; off > 0; off >>= 1) {
            if (tid < off) red[tid] += red[tid + off];
            __syncthreads();
        }
        if (tid == 0) s_sc[m] = red[0] * SCALE * conf[v];
        __syncthreads();
    }
    if (tid == 0) {
        float mx = s_sc[0];
        for (int m = 1; m < M; ++m) mx = fmaxf(mx, s_sc[m]);
        float w[8], sum = 0.f;
        for (int m = 0; m < M; ++m) { w[m] = expf(s_sc[m] - mx); sum += w[m]; }
        for (int m = 0; m < M; ++m) s_sc[m] = w[m] / sum;
    }
    __syncthreads();
#pragma unroll
    for (int r = 0; r < 4; ++r) {
        int e = r * 256 + tid;
        int j = e & 511;
        float lr = 0.f, li = 0.f;
#pragma unroll
        for (int ss = 0; ss < SPLIT; ++ss) {
            const float* bp = P2 + ((size_t)ss * NTOK + v) * LDKV;
            lr += bp[j];
            li += bp[512 + j];
        }
        float zf = cepi1(lr, li, e >= 512);
        float ctx = 0.f;
        for (int m = 0; m < M; ++m)
            ctx += s_sc[m] * Vmem[(size_t)m * NTOK * D2 + (size_t)v * D2 + e];
        z[(size_t)v * D2 + e] = zf + 0.1f * ctx;
    }
}

// ---------------- finish (round-4 bitwise); FROMP recomputes z from P2 (d=0) ----------
template<bool FROMP>
__global__ __launch_bounds__(512) void finish_kernel(float* __restrict__ z,
                                                     const float* __restrict__ P2,
                                                     const float* __restrict__ sym,
                                                     const float* __restrict__ snorm,
                                                     const float* __restrict__ con,
                                                     const float* __restrict__ conT,
                                                     const float* __restrict__ symP,
                                                     float* __restrict__ conf,
                                                     float* __restrict__ symErr,
                                                     float* __restrict__ conErr) {
    int t0 = blockIdx.x;
    int tid = threadIdx.x;
    __shared__ __align__(16) float s_z[D2];
    __shared__ float s_red[512];
    __shared__ int   s_idx[512];
    __shared__ float s_res[4];
    __shared__ int   s_si[1];
    __shared__ float s_pd[256], s_pc[256];

    if (FROMP) {
        float lr = 0.f, li = 0.f;
#pragma unroll
        for (int ss = 0; ss < SPLIT; ++ss) {
            const float* bp = P2 + ((size_t)ss * NTOK + t0) * LDKV;
            lr += bp[tid];
            li += bp[512 + tid];
        }
        float m = sqrtf(lr * lr + li * li + EPSF);
        float inv = 1.0f / (1.0f + m);
        s_z[tid]       = tanhf(lr * inv);
        s_z[512 + tid] = tanhf(li * inv);
    } else {
        if (tid < 256) ((float4*)s_z)[tid] = ((const float4*)(z + (size_t)t0 * D2))[tid];
    }
    __syncthreads();

    // ||z||^2
    {
        float a = s_z[tid], b = s_z[512 + tid];
        s_red[tid] = a * a + b * b;
        __syncthreads();
        for (int off = 256; off > 0; off >>= 1) {
            if (tid < off) s_red[tid] += s_red[tid + off];
            __syncthreads();
        }
        if (tid == 0) s_res[0] = s_red[0];
        __syncthreads();
    }

    // sym distance + argmin (first-min tie-break)
    {
        float dot = 0.f;
#pragma unroll
        for (int s = 0; s < SPLIT; ++s)
            dot += symP[((size_t)s * NTOK + t0) * NSYM + tid];
        float d = (s_res[0] + snorm[tid]) - 2.f * dot;
        s_red[tid] = d; s_idx[tid] = tid;
        __syncthreads();
        for (int off = 256; off > 0; off >>= 1) {
            if (tid < off) {
                float o = s_red[tid + off]; int oi = s_idx[tid + off];
                if (o < s_red[tid] || (o == s_red[tid] && oi < s_idx[tid])) {
                    s_red[tid] = o; s_idx[tid] = oi;
                }
            }
            __syncthreads();
        }
        if (tid == 0) { s_res[1] = s_red[0]; s_si[0] = s_idx[0]; }
        __syncthreads();
    }

    // conf, straight-through update, symErr
    {
        int si = s_si[0];
        if (tid == 0) conf[t0] = 1.0f / (1.0f + s_res[1]);
        const float* crow = sym + (size_t)si * D2;
        float errp = 0.f;
#pragma unroll
        for (int r = 0; r < 2; ++r) {
            int e = r * 512 + tid;
            float zf = s_z[e];
            float diff = crow[e] - zf;
            errp += diff * diff;
            float zn = zf + diff;      // zs = z + (c - z)
            s_z[e] = zn;
            z[(size_t)t0 * D2 + e] = zn;
        }
        s_red[tid] = errp;
        __syncthreads();
        for (int off = 256; off > 0; off >>= 1) {
            if (tid < off) s_red[tid] += s_red[tid + off];
            __syncthreads();
        }
        if (tid == 0) symErr[t0] += s_red[0];
        __syncthreads();
    }

    // ||zs||^2
    {
        float a = s_z[tid], b = s_z[512 + tid];
        s_red[tid] = a * a + b * b;
        __syncthreads();
        for (int off = 256; off > 0; off >>= 1) {
            if (tid < off) s_red[tid] += s_red[tid + off];
            __syncthreads();
        }
        if (tid == 0) s_res[2] = s_red[0];
        __syncthreads();
    }

    // con quantize
    if (tid < 256) {
        int c = tid & 63, sl = tid >> 6;
        float pd = 0.f, pc = 0.f;
        int k0 = sl * 256;
#pragma unroll 4
        for (int k = k0; k < k0 + 256; ++k) {
            float w = conT[(size_t)k * NCON + c];
            pd += w * s_z[k];
            pc += w * w;
        }
        s_pd[tid] = pd; s_pc[tid] = pc;
    }
    __syncthreads();
    if (tid < 64) {
        float dot = ((s_pd[tid] + s_pd[64 + tid]) + s_pd[128 + tid]) + s_pd[192 + tid];
        float cn2 = ((s_pc[tid] + s_pc[64 + tid]) + s_pc[128 + tid]) + s_pc[192 + tid];
        s_red[tid] = (s_res[2] + cn2) - 2.f * dot;
        s_idx[tid] = tid;
    }
    __syncthreads();
    for (int off = 32; off > 0; off >>= 1) {
        if (tid < off) {
            float o = s_red[tid + off]; int oi = s_idx[tid + off];
            if (o < s_red[tid] || (o == s_red[tid] && oi < s_idx[tid])) {
                s_red[tid] = o; s_idx[tid] = oi;
            }
        }
        __syncthreads();
    }
    int ci0 = s_idx[0];
    __syncthreads();

    // conErr
    {
        const float* crow = con + (size_t)ci0 * D2;
        float pp = 0.f;
#pragma unroll
        for (int r = 0; r < 2; ++r) {
            int e = r * 512 + tid;
            float diff = crow[e] - s_z[e];
            pp += diff * diff;
        }
        s_red[tid] = pp;
        __syncthreads();
        for (int off = 256; off > 0; off >>= 1) {
            if (tid < off) s_red[tid] += s_red[tid + off];
            __syncthreads();
        }
        if (tid == 0) conErr[t0] += s_red[0];
    }
}

// ---------------- final: deccomb+scatter (blocks < BS_TOT) + hist+loss (last block) ------
__global__ __launch_bounds__(256) void final_kernel(const int* __restrict__ x,
                                                    const float* __restrict__ decP,
                                                    const float* __restrict__ dec_b,
                                                    const float* __restrict__ symErr,
                                                    const float* __restrict__ conErr,
                                                    float* __restrict__ out) {
    int bid = blockIdx.x, tid = threadIdx.x;
    if (bid < BS_TOT) {
        int v = x[bid];
        float val = 0.f;
#pragma unroll
        for (int s = 0; s < SPLIT; ++s)
            val += decP[((size_t)s * NTOK + v) * VOCAB + tid];
        out[(size_t)bid * VOCAB + tid] = val + dec_b[tid];
    } else {
        __shared__ int h[256];
        __shared__ double rs[256], rc[256];
        h[tid] = 0;
        __syncthreads();
        for (int i = tid; i < BS_TOT; i += 256) atomicAdd(&h[x[i]], 1);
        __syncthreads();
        rs[tid] = (double)h[tid] * (double)symErr[tid];
        rc[tid] = (double)h[tid] * (double)conErr[tid];
        __syncthreads();
        for (int off = 128; off > 0; off >>= 1) {
            if (tid < off) { rs[tid] += rs[tid + off]; rc[tid] += rc[tid + off]; }
            __syncthreads();
        }
        if (tid == 0) {
            const double denom = (double)BS_TOT * (double)D2;
            out[(size_t)BS_TOT * VOCAB]     = (float)(1.25 * rs[0] / denom);
            out[(size_t)BS_TOT * VOCAB + 1] = (float)(1.25 * rc[0] / denom);
        }
    }
}

// ---------------- host ----------------
extern "C" void kernel_launch(void* const* d_in, const int* in_sizes, int n_in,
                              void* d_out, int out_size, void* d_ws, size_t ws_size,
                              hipStream_t stream) {
    const int*   x     = (const int*)  d_in[0];
    const float* mag   = (const float*)d_in[1];
    const float* phase = (const float*)d_in[2];
    const float* Wr    = (const float*)d_in[3];
    const float* Wi    = (const float*)d_in[4];
    const float* qw    = (const float*)d_in[5];
    const float* qb    = (const float*)d_in[6];
    const float* kw    = (const float*)d_in[7];
    const float* kb    = (const float*)d_in[8];
    const float* vw    = (const float*)d_in[9];
    const float* vb    = (const float*)d_in[10];
    const float* dec_w = (const float*)d_in[11];
    const float* dec_b = (const float*)d_in[12];
    const float* sym   = (const float*)d_in[13];
    const float* con   = (const float*)d_in[14];
    float* out = (float*)d_out;

    float* w = (float*)d_ws;
    auto take = [&](size_t n) { float* r = w; w += n; return r; };
    float* bufZ   = take((size_t)NTOK * D2);
    float* CKV    = take((size_t)D2 * LDKV);        // [cell 1024 | kw 512 | vw 1024]
    float* qwT    = take((size_t)D2 * DD);
    float* symT   = take((size_t)D2 * NSYM);
    float* decT   = take((size_t)D2 * VOCAB);
    float* conT   = take((size_t)D2 * NCON);
    float* P2     = take((size_t)SPLIT * NTOK * LDKV);
    float* cellPa = take((size_t)SPLIT * NTOK * D2);
    float* cellPb = take((size_t)SPLIT * NTOK * D2);
    float* QP     = take((size_t)SPLIT * NTOK * DD);
    float* symP   = take((size_t)SPLIT * NTOK * NSYM);
    float* decP   = take((size_t)SPLIT * NTOK * VOCAB);
    float* Kmem   = take((size_t)5 * NTOK * DD);
    float* Vmem   = take((size_t)5 * NTOK * D2);
    float* snorm  = take(NSYM);
    float* conf   = take(NTOK);
    float* symErr = take(NTOK);
    float* conErr = take(NTOK);

    setup_kernel<<<256, 256, 0, stream>>>(mag, phase, Wr, Wi, qw, kw, vw, dec_w, sym, con,
                                          bufZ, CKV, qwT, symT, decT, conT, snorm,
                                          symErr, conErr);

    // d = 0: cell-only gemm, sym gemm (FROMP), finish (FROMP)
    gemm_kernel<false><<<dim3(16, 4, SPLIT), 256, 0, stream>>>(CKV, LDKV, bufZ, D2, P2, LDKV);
    gemm_kernel<true><<<dim3(8, 4, SPLIT), 256, 0, stream>>>(symT, NSYM, P2, LDKV, symP, NSYM);
    finish_kernel<true><<<NTOK, 512, 0, stream>>>(bufZ, P2, sym, snorm, con, conT, symP,
                                                  conf, symErr, conErr);

    for (int d = 1; d < NDEPTH; ++d) {
        // cell + KV(slot d-1) fused gemm from z
        gemm_kernel<false><<<dim3(40, 4, SPLIT), 256, 0, stream>>>(CKV, LDKV, bufZ, D2, P2, LDKV);
        // Q gemm staging from P2 cell partials (epi recompute)
        gemm_kernel<true><<<dim3(8, 4, SPLIT), 256, 0, stream>>>(qwT, DD, P2, LDKV, QP, DD);
        // attend: kvcomb slot d-1 + scores + z = epi + 0.1*ctx
        attend_kernel<<<NTOK, 256, 0, stream>>>(bufZ, P2, QP, qb, kb, vb, Kmem, Vmem, conf, d);
        // sym gemm from post-attend z
        gemm_kernel<false><<<dim3(8, 4, SPLIT), 256, 0, stream>>>(symT, NSYM, bufZ, D2, symP, NSYM);
        finish_kernel<false><<<NTOK, 512, 0, stream>>>(bufZ, nullptr, sym, snorm, con, conT,
                                                       symP, conf, symErr, conErr);
    }

    // look cells: chain through partials (epi recomputed in staging)
    gemm_kernel<false><<<dim3(16, 4, SPLIT), 256, 0, stream>>>(CKV, LDKV, bufZ, D2, cellPa, D2);
    gemm_kernel<true><<<dim3(16, 4, SPLIT), 256, 0, stream>>>(CKV, LDKV, cellPa, D2, cellPb, D2);
    gemm_kernel<true><<<dim3(16, 4, SPLIT), 256, 0, stream>>>(CKV, LDKV, cellPb, D2, cellPa, D2);
    // decode gemm from last look partials
    gemm_kernel<true><<<dim3(4, 4, SPLIT), 256, 0, stream>>>(decT, VOCAB, cellPa, D2, decP, VOCAB);
    // deccomb+scatter + hist+loss
    final_kernel<<<BS_TOT + 1, 256, 0, stream>>>(x, decP, dec_b, symErr, conErr, out);
}